// Round 10
// baseline (142.366 us; speedup 1.0000x reference)
//
#include <hip/hip_runtime.h>

#define S 128
#define WPB 2                              // waves per block (128 threads)
#define BROWS 16                           // output rows per wave
#define STROWS 18                          // staged rows per wave (window)
#define NBANDS (S / BROWS)                 // 8 bands per plane
#define TOTAL_WAVES (1024 * NBANDS)        // 8192
#define NBLOCKS (TOTAL_WAVES / WPB)        // 4096

typedef const __attribute__((address_space(1))) void* gas_t;
typedef __attribute__((address_space(3))) void* las_t;

__global__ __launch_bounds__(128, 4) void pairwise_potential_kernel(
    const float* __restrict__ x, const float* __restrict__ w1,
    const float* __restrict__ w2, float* __restrict__ out)
{
    __shared__ float tile[WPB][STROWS][S];     // 2 x 9216 B = 18432 B/block

    const int tid = threadIdx.x;
    const int wid = tid >> 6;      // wave in block
    const int l   = tid & 63;      // lane
    const int qc  = l & 31;        // quad-column 0..31
    const int rg  = l >> 5;        // 0: band rows 0-7, 1: band rows 8-15

    const int gw    = blockIdx.x * WPB + wid;
    const int plane = gw >> 3;                 // 8 bands/plane
    const int band  = gw & 7;
    const int r0    = band * BROWS;
    const int c     = plane & 63;
    const int col   = qc * 4;
    const int st    = min(max(r0 - 1, 0), S - STROWS);   // first staged row

    const float* xp  = x   + ((size_t)plane << 14);
    const float* w1p = w1  + (size_t)c * (S * S);
    const float* w2p = w2  + (size_t)c * (S * S);
    float*       op  = out + ((size_t)plane << 14);

    const float NL  = -0.72134752044f;    // -0.5 * log2(e)
    const float E1N = 0.06739229552f;     // exp(-0.5)/9        (d = 1)
    const float E2N = 0.05478541015f;     // exp(-sqrt2/2)/9    (d = sqrt2)
    const float C9  = 0.11111111111f;     // exp(0)/9           (center term)
    const float W2C = 1.07298380550f;     // (4 + 4*sqrt(2)) / 9

    // halo columns (clamped address; value masked after load)
    const int cl = (qc == 0)  ? 0       : col - 1;
    const int cr = (qc == 31) ? S - 1   : col + 4;

    // ---- stage 18 contiguous rows into this wave's LDS slice (9 x 1KB) ----
    #pragma unroll
    for (int k = 0; k < 9; ++k) {
        const float* src = xp + (st + 2 * k) * S + l * 4;
        __builtin_amdgcn_global_load_lds((gas_t)src, (las_t)&tile[wid][2 * k][0], 16, 0, 0);
    }

    // w loads for sub-quad 0 issued under the staging drain
    const int rb0 = r0 + rg * 8;          // sub-quad 0 first row
    float4 w1v0[4], w2v0[4];
    #pragma unroll
    for (int q = 0; q < 4; ++q) {
        w1v0[q] = *(const float4*)(w1p + (rb0 + q) * S + col);
        w2v0[q] = *(const float4*)(w2p + (rb0 + q) * S + col);
    }

    asm volatile("s_waitcnt vmcnt(0)" ::: "memory");   // wave-private drain
    __builtin_amdgcn_sched_barrier(0);

    float4 w1v1[4], w2v1[4];               // sub-quad 1 w loads: issue early, use late
    const int rb1 = rb0 + 4;
    #pragma unroll
    for (int q = 0; q < 4; ++q) {
        w1v1[q] = *(const float4*)(w1p + (rb1 + q) * S + col);
        w2v1[q] = *(const float4*)(w2p + (rb1 + q) * S + col);
    }

    #pragma unroll
    for (int sq = 0; sq < 2; ++sq) {
        const int rbase = (sq == 0) ? rb0 : rb1;
        const float4* w1v = (sq == 0) ? w1v0 : w1v1;
        const float4* w2v = (sq == 0) ? w2v0 : w2v1;

        // 6 window rows: ds_read_b128 core + 2 scalar halo reads (fused to ds_read2)
        float m[6][6];
        #pragma unroll
        for (int j = 0; j < 6; ++j) {
            const int lr = min(max(rbase - 1 + j - st, 0), STROWS - 1);
            const float4 v = *(const float4*)&tile[wid][lr][col];
            float lf = tile[wid][lr][cl];
            float rf = tile[wid][lr][cr];
            if (qc == 0)  lf = 0.f;                  // col -1 zero-pad
            if (qc == 31) rf = 0.f;                  // col 128 zero-pad
            m[j][0] = lf; m[j][1] = v.x; m[j][2] = v.y; m[j][3] = v.z; m[j][4] = v.w; m[j][5] = rf;
        }
        if (rbase == 0) {                            // x row -1
            #pragma unroll
            for (int t = 0; t < 6; ++t) m[0][t] = 0.f;
        }
        if (rbase + 4 == S) {                        // x row 128
            #pragma unroll
            for (int t = 0; t < 6; ++t) m[5][t] = 0.f;
        }

        float* opr = op + rbase * S + col;
        #pragma unroll
        for (int rq = 0; rq < 4; ++rq) {
            const float* m0 = m[rq];
            const float* m1 = m[rq + 1];
            const float* m2 = m[rq + 2];
            const float* w1a = &w1v[rq].x;
            const float* w2a = &w2v[rq].x;
            float4 o;
            float* ov = &o.x;
            #pragma unroll
            for (int k = 0; k < 4; ++k) {
                const float cen = m0[k];      // X(h-1, w-1): window root
                float d;
                d = cen - m0[k + 1]; const float a0 = __builtin_amdgcn_exp2f(d * d * NL);
                d = cen - m0[k + 2]; const float a1 = __builtin_amdgcn_exp2f(d * d * NL);
                d = cen - m1[k];     const float a2 = __builtin_amdgcn_exp2f(d * d * NL);
                d = cen - m2[k];     const float a3 = __builtin_amdgcn_exp2f(d * d * NL);
                d = cen - m1[k + 1]; const float b0 = __builtin_amdgcn_exp2f(d * d * NL);
                d = cen - m1[k + 2]; const float b1 = __builtin_amdgcn_exp2f(d * d * NL);
                d = cen - m2[k + 1]; const float b2 = __builtin_amdgcn_exp2f(d * d * NL);
                d = cen - m2[k + 2]; const float b3 = __builtin_amdgcn_exp2f(d * d * NL);
                const float s1 = (a0 + a1) + (a2 + a3);
                const float s2 = (b0 + b1) + (b2 + b3);
                const float fN = fmaf(E2N, s2, fmaf(E1N, s1, C9));   // first/9
                ov[k] = fmaf(w1a[k], fN, w2a[k] * W2C);
            }
            *reinterpret_cast<float4*>(opr + rq * S) = o;
        }
    }
}

extern "C" void kernel_launch(void* const* d_in, const int* in_sizes, int n_in,
                              void* d_out, int out_size, void* d_ws, size_t ws_size,
                              hipStream_t stream) {
    const float* x  = (const float*)d_in[0];
    const float* w1 = (const float*)d_in[1];
    const float* w2 = (const float*)d_in[2];
    float* out = (float*)d_out;
    pairwise_potential_kernel<<<NBLOCKS, 128, 0, stream>>>(x, w1, w2, out);
}

// Round 11
// 135.840 us; speedup vs baseline: 1.0480x; 1.0480x over previous
//
#include <hip/hip_runtime.h>
#include <stdint.h>

#define S 128
#define NPLANES 1024                        // B*C
#define NTHREADS (NPLANES * S * (S / 4))    // 4,194,304 (one float4 of one row each)
#define NBLOCKS (NTHREADS / 256)            // 16384

typedef float f4 __attribute__((ext_vector_type(4)));

__global__ __launch_bounds__(256, 8) void pairwise_potential_kernel(
    const float* __restrict__ x, const float* __restrict__ w1,
    const float* __restrict__ w2, float* __restrict__ out)
{
    const int t     = blockIdx.x * 256 + threadIdx.x;
    const int seg   = t & 31;           // which float4 within the row
    const int row   = (t >> 5) & (S - 1);
    const int plane = t >> 12;          // b*64 + c
    const int c     = plane & 63;
    const int col   = seg << 2;

    const float* xp = x + ((size_t)plane << 14);
    const int rm = max(row - 1, 0);
    const int rp = min(row + 1, S - 1);
    const float* pm = xp + rm  * S + col;
    const float* p0 = xp + row * S + col;
    const float* pp = xp + rp  * S + col;
    const int lo = (seg == 0)  ? 0 : -1;   // clamped halo offsets
    const int ho = (seg == 31) ? 3 :  4;
    const float* w1p = w1 + (size_t)c * (S * S) + row * S + col;
    const float* w2p = w2 + (size_t)c * (S * S) + row * S + col;

    // ---- 11 loads as volatile asm: allocator CANNOT re-serialize this burst ----
    f4 va, vb, vc, w1v, w2v;
    float la, lb, lc, ha, hb, hc;
#define LD4(dst, p) asm volatile("global_load_dwordx4 %0, %1, off" \
                                 : "=v"(dst) : "v"((uint64_t)(uintptr_t)(p)))
#define LD1(dst, p) asm volatile("global_load_dword %0, %1, off"   \
                                 : "=v"(dst) : "v"((uint64_t)(uintptr_t)(p)))
    LD4(va, pm); LD4(vb, p0); LD4(vc, pp);
    LD4(w1v, w1p); LD4(w2v, w2p);
    LD1(la, pm + lo); LD1(lb, p0 + lo); LD1(lc, pp + lo);
    LD1(ha, pm + ho); LD1(hb, p0 + ho); LD1(hc, pp + ho);
#undef LD4
#undef LD1
    asm volatile("s_waitcnt vmcnt(0)" ::: "memory");
    __builtin_amdgcn_sched_barrier(0);     // rule #18: no consumer hoists past the wait

    // ---- zero-pad masking (branchless) ----
    if (seg == 0)  { la = 0.f; lb = 0.f; lc = 0.f; }
    if (seg == 31) { ha = 0.f; hb = 0.f; hc = 0.f; }
    const float mt = (row == 0)     ? 0.f : 1.f;
    const float mb = (row == S - 1) ? 0.f : 1.f;
    va *= mt; la *= mt; ha *= mt;
    vc *= mb; lc *= mb; hc *= mb;

    float m0[6] = { la, va.x, va.y, va.z, va.w, ha };
    float m1[6] = { lb, vb.x, vb.y, vb.z, vb.w, hb };
    float m2[6] = { lc, vc.x, vc.y, vc.z, vc.w, hc };

    const float NL  = -0.72134752044f;    // -0.5 * log2(e)
    const float E1N = 0.06739229552f;     // exp(-0.5)/9        (d = 1)
    const float E2N = 0.05478541015f;     // exp(-sqrt2/2)/9    (d = sqrt2)
    const float C9  = 0.11111111111f;     // exp(0)/9           (center term)
    const float W2C = 1.07298380550f;     // (4 + 4*sqrt(2)) / 9

    float4 o;
    float* ov = &o.x;
    #pragma unroll
    for (int k = 0; k < 4; ++k) {
        const float cen = m0[k];          // X(h-1, w-1): window root
        float d;
        d = cen - m0[k + 1]; const float a0 = __builtin_amdgcn_exp2f(d * d * NL);
        d = cen - m0[k + 2]; const float a1 = __builtin_amdgcn_exp2f(d * d * NL);
        d = cen - m1[k];     const float a2 = __builtin_amdgcn_exp2f(d * d * NL);
        d = cen - m2[k];     const float a3 = __builtin_amdgcn_exp2f(d * d * NL);
        d = cen - m1[k + 1]; const float b0 = __builtin_amdgcn_exp2f(d * d * NL);
        d = cen - m1[k + 2]; const float b1 = __builtin_amdgcn_exp2f(d * d * NL);
        d = cen - m2[k + 1]; const float b2 = __builtin_amdgcn_exp2f(d * d * NL);
        d = cen - m2[k + 2]; const float b3 = __builtin_amdgcn_exp2f(d * d * NL);
        const float s1 = (a0 + a1) + (a2 + a3);
        const float s2 = (b0 + b1) + (b2 + b3);
        const float w1k = (k == 0) ? w1v.x : (k == 1) ? w1v.y : (k == 2) ? w1v.z : w1v.w;
        const float w2k = (k == 0) ? w2v.x : (k == 1) ? w2v.y : (k == 2) ? w2v.z : w2v.w;
        const float fN = fmaf(E2N, s2, fmaf(E1N, s1, C9));   // first/9
        ov[k] = fmaf(w1k, fN, w2k * W2C);
    }
    float* op = out + ((size_t)plane << 14) + row * S + col;
    *reinterpret_cast<float4*>(op) = o;
}

extern "C" void kernel_launch(void* const* d_in, const int* in_sizes, int n_in,
                              void* d_out, int out_size, void* d_ws, size_t ws_size,
                              hipStream_t stream) {
    const float* x  = (const float*)d_in[0];
    const float* w1 = (const float*)d_in[1];
    const float* w2 = (const float*)d_in[2];
    float* out = (float*)d_out;
    pairwise_potential_kernel<<<NBLOCKS, 256, 0, stream>>>(x, w1, w2, out);
}